// Round 1
// baseline (523.832 us; speedup 1.0000x reference)
//
#include <hip/hip_runtime.h>
#include <float.h>

// IQE quasimetric:  per row, measure of union of [x_j, y_j] over j with x_j < y_j.
// Identity: a = sort(valid ? x : FLT_MAX), b = sort(valid ? y : FLT_MAX)
//           result = sum_i max(0, b_i - max(a_i, b_{i-1})),  b_{-1} = -inf.
//
// Layout: 4 lanes per row, 32 elements per lane (e = 32*g + r), 16 rows per wave.
// All cross-lane exchange masks are 1 and 2 -> DPP quad_perm (VALU pipe, zero LDS).
// Bitonic-128: 25 in-lane substeps + only 3 cross substeps (vs 10 at 16 lanes/row).
// Input->position assignment is an arbitrary per-row permutation (sort input order
// is irrelevant; x/y pairing preserved), so loads are 8 contiguous float4 per array.

constexpr int D = 128;
#define INF __builtin_huge_valf()

__device__ inline float med3(float a, float b, float c) {
    return __builtin_amdgcn_fmed3f(a, b, c);
}

// DPP quad_perm move (VALU pipe). CTRL 0x00-0xFF = quad_perm.
template<int CTRL>
__device__ inline float dppmov(float v) {
    int i = __builtin_amdgcn_mov_dpp(__float_as_int(v), CTRL, 0xF, 0xF, true);
    return __int_as_float(i);
}
constexpr int QP_XOR1 = 0xB1; // quad_perm [1,0,3,2]  : lane ^= 1
constexpr int QP_XOR2 = 0x4E; // quad_perm [2,3,0,1]  : lane ^= 2
constexpr int QP_SHR1 = 0x90; // quad_perm [0,0,1,2]  : lane g <- g-1 (g=0 self)

// compile-time-direction in-lane CE
__device__ inline void cea(float& u, float& v) { float lo = fminf(u, v), hi = fmaxf(u, v); u = lo; v = hi; }
__device__ inline void ced(float& u, float& v) { float lo = fminf(u, v), hi = fmaxf(u, v); u = hi; v = lo; }
// per-lane-direction in-lane CE: s = +-INF selector; lo slot u gets med3(u,v,s)
__device__ inline void cek(float& u, float& v, float s) {
    float lo = med3(u, v, s), hi = med3(u, v, -s); u = lo; v = hi;
}

// in-lane substep, compile-time stage K (direction from r&K) and pair distance J
template<int K, int J>
__device__ inline void sub_ct(float (&v)[32]) {
    #pragma unroll
    for (int r = 0; r < 32; r++)
        if (!(r & J)) { if (!(r & K)) cea(v[r], v[r + J]); else ced(v[r], v[r + J]); }
}
// in-lane substep, runtime direction selector s (stage bit lives in lane id)
template<int J>
__device__ inline void sub_rt(float (&v)[32], float s) {
    #pragma unroll
    for (int r = 0; r < 32; r++)
        if (!(r & J)) cek(v[r], v[r + J], s);
}
// cross-lane substep via quad_perm: partner = lane^mask; each lane keeps min/max per sel
template<int CTRL>
__device__ inline void cross(float (&v)[32], float sel) {
    #pragma unroll
    for (int r = 0; r < 32; r++) {
        float t = dppmov<CTRL>(v[r]);
        v[r] = med3(v[r], t, sel);
    }
}

__global__ __launch_bounds__(256) void iqe_union_kernel(
    const float* __restrict__ x, const float* __restrict__ y,
    float* __restrict__ out, int B)
{
    const int tid = threadIdx.x;
    const int g   = tid & 3;                        // lane within 4-lane row group
    const int row = blockIdx.x * 64 + (tid >> 2);   // 64 rows per 256-thread block
    if (row >= B) return;

    const size_t rbase = (size_t)row * D;
    float a[32], b[32];
    // lane g takes float4 chunks [16t + 4g .. +4) — 64B/row per instruction, dense.
    #pragma unroll
    for (int t = 0; t < 8; t++) {
        *reinterpret_cast<float4*>(&a[4 * t]) = *reinterpret_cast<const float4*>(x + rbase + 16 * t + 4 * g);
        *reinterpret_cast<float4*>(&b[4 * t]) = *reinterpret_cast<const float4*>(y + rbase + 16 * t + 4 * g);
    }
    #pragma unroll
    for (int r = 0; r < 32; r++) {
        const bool v = a[r] < b[r];
        a[r] = v ? a[r] : FLT_MAX;
        b[r] = v ? b[r] : FLT_MAX;
    }

    // per-lane bit signs and +-INF selectors (element bit5 = g&1, bit6 = g&2)
    const float S1 = (g & 1) ? 1.f : -1.f;
    const float S2 = (g & 2) ? 1.f : -1.f;
    const float M1 = S1 * INF;            // in-lane selector, stage dir bit = g&1
    const float M2 = S2 * INF;            // in-lane selector, stage dir bit = g&2
    const float C1 = -S1 * S2 * INF;      // stage-64 cross (mask1, dir bit g&2)

    // ---- bitonic sort of 128 (e = 32*g + r), arrays a and b in lockstep ----
    // stages k=2..16: fully in-lane, compile-time directions
    sub_ct<2, 1>(a);  sub_ct<2, 1>(b);
    sub_ct<4, 2>(a);  sub_ct<4, 2>(b);
    sub_ct<4, 1>(a);  sub_ct<4, 1>(b);
    sub_ct<8, 4>(a);  sub_ct<8, 4>(b);
    sub_ct<8, 2>(a);  sub_ct<8, 2>(b);
    sub_ct<8, 1>(a);  sub_ct<8, 1>(b);
    sub_ct<16, 8>(a); sub_ct<16, 8>(b);
    sub_ct<16, 4>(a); sub_ct<16, 4>(b);
    sub_ct<16, 2>(a); sub_ct<16, 2>(b);
    sub_ct<16, 1>(a); sub_ct<16, 1>(b);
    // stage k=32: in-lane, direction by g&1
    sub_rt<16>(a, M1); sub_rt<16>(b, M1);
    sub_rt<8>(a, M1);  sub_rt<8>(b, M1);
    sub_rt<4>(a, M1);  sub_rt<4>(b, M1);
    sub_rt<2>(a, M1);  sub_rt<2>(b, M1);
    sub_rt<1>(a, M1);  sub_rt<1>(b, M1);
    // stage k=64: one cross substep (mask1), then in-lane by g&2
    cross<QP_XOR1>(a, C1); cross<QP_XOR1>(b, C1);
    sub_rt<16>(a, M2); sub_rt<16>(b, M2);
    sub_rt<8>(a, M2);  sub_rt<8>(b, M2);
    sub_rt<4>(a, M2);  sub_rt<4>(b, M2);
    sub_rt<2>(a, M2);  sub_rt<2>(b, M2);
    sub_rt<1>(a, M2);  sub_rt<1>(b, M2);
    // stage k=128: ascending everywhere; two cross substeps then in-lane
    cross<QP_XOR2>(a, M2); cross<QP_XOR2>(b, M2);
    cross<QP_XOR1>(a, M1); cross<QP_XOR1>(b, M1);
    sub_ct<128, 16>(a); sub_ct<128, 16>(b);
    sub_ct<128, 8>(a);  sub_ct<128, 8>(b);
    sub_ct<128, 4>(a);  sub_ct<128, 4>(b);
    sub_ct<128, 2>(a);  sub_ct<128, 2>(b);
    sub_ct<128, 1>(a);  sub_ct<128, 1>(b);

    // ---- epilogue: sum max(0, b_e - max(a_e, b_{e-1})) ----
    float prev = dppmov<QP_SHR1>(b[31]);    // previous lane's last b
    if (g == 0) prev = -FLT_MAX;            // b_{-1} = -inf (row boundary)
    float c = 0.f;
    #pragma unroll
    for (int r = 0; r < 32; r++) {
        c += fmaxf(0.f, b[r] - fmaxf(a[r], prev));
        prev = b[r];
    }
    // reduce over the 4-lane group (quad_perm butterfly)
    c += dppmov<QP_XOR1>(c);
    c += dppmov<QP_XOR2>(c);
    if (g == 0) out[row] = c;
}

extern "C" void kernel_launch(void* const* d_in, const int* in_sizes, int n_in,
                              void* d_out, int out_size, void* d_ws, size_t ws_size,
                              hipStream_t stream) {
    const float* x = (const float*)d_in[0];
    const float* y = (const float*)d_in[1];
    float* out = (float*)d_out;
    const int B = in_sizes[0] / D;            // 524288
    const int blocks = (B + 63) / 64;         // 64 rows per 256-thread block
    iqe_union_kernel<<<blocks, 256, 0, stream>>>(x, y, out, B);
}